// Round 3
// baseline (530.748 us; speedup 1.0000x reference)
//
#include <hip/hip_runtime.h>
#include <hip/hip_cooperative_groups.h>

namespace cg = cooperative_groups;

#define DHW (64*128*128)
#define MIR 32

// accumulator layout in d_ws (floats)
#define OFF_CEM   0        // [MIR][49]: nll, cardp[2][8], inter[2][8], cardg[2][8]
#define OFF_SEGM  1568     // [MIR][2][306]: cnum[17][16] (16..271), wsum[17] (272..288), cnt[17] (289..305)
#define OFF_PULLM 21152    // [MIR][2][17]
#define OFF_CTR   22240    // [2][17][16]
#define OFF_CNT   22784    // [2][17]
#define ACC_FLOATS 22818
#define OFF_EDGE_BYTES 92160   // byte offset into ws: 2 * DHW/4 bytes = 512 KiB edge-bit cache

typedef __bf16 bf16x8 __attribute__((ext_vector_type(8)));
typedef float f32x4 __attribute__((ext_vector_type(4)));
union FragU { short s[8]; bf16x8 v; };

__device__ inline short f2bf(float f) {   // RTNE float->bf16
    union { float f; unsigned u; } v; v.f = f;
    unsigned r = v.u + 0x7FFF + ((v.u >> 16) & 1);
    return (short)(r >> 16);
}

// boundary bits for 4 consecutive-in-x voxels (x % 4 == 0), fully unrolled
__device__ inline unsigned edge4(const int* __restrict__ L, int vb, int4 c) {
    int x = vb & 127, y = (vb >> 7) & 127, z = vb >> 14;
    int xm = max(x - 1, 0), xp = min(x + 4, 127);
    unsigned b0 = 0, b1 = 0, b2 = 0, b3 = 0;
#pragma unroll
    for (int dz = -1; dz <= 1; ++dz) {
        int zz = min(max(z + dz, 0), 63);
#pragma unroll
        for (int dy = -1; dy <= 1; ++dy) {
            int yy = min(max(y + dy, 0), 127);
            const int* row = L + (zz << 14) + (yy << 7);
            int4 r = *reinterpret_cast<const int4*>(&row[x]);
            int rm = row[xm], rp = row[xp];
            b0 |= (rm != c.x) | (r.x != c.x) | (r.y != c.x);
            b1 |= (r.x != c.y) | (r.y != c.y) | (r.z != c.y);
            b2 |= (r.y != c.z) | (r.z != c.z) | (r.w != c.z);
            b3 |= (r.z != c.w) | (r.w != c.w) | (rp != c.w);
        }
    }
    return b0 | (b1 << 1) | (b2 << 2) | (b3 << 3);
}

// ---------------- task bodies (shared by fused + fallback) ----------------

// seg task t in [0,2048): b=t&1, blk=t>>1; cacc = 288-float LDS scratch
__device__ void seg_task(const float* __restrict__ embed, const int* __restrict__ labels,
                         float* __restrict__ acc, int t, float* cacc) {
    int tid = threadIdx.x;
    int b = t & 1;
    int blk = t >> 1;
    int mir = blk & (MIR - 1);
    int lane = tid & 63;
    int wv = tid >> 6;
    int m = lane & 15;
    int quad = lane >> 4;

    const int* L = labels + (size_t)b * DHW;
    const float* E = embed + (size_t)b * 16 * DHW + (size_t)m * DHW;

    int waveId = blk * 4 + wv;
    int wavebase = waveId * 256;

    unsigned eb_own;
    {
        int own_off = wavebase + lane * 4;
        int4 lo = *reinterpret_cast<const int4*>(&L[own_off]);
        eb_own = edge4(L, own_off, lo);
    }
    {   // cache edge bits for the pull pass
        unsigned char* EB = (unsigned char*)acc + OFF_EDGE_BYTES + ((size_t)b << 18);
        EB[blk * 256 + tid] = (unsigned char)eb_own;
    }

    int off = wavebase + quad * 8;

    f32x4 acc_c = {0.f, 0.f, 0.f, 0.f};
    f32x4 acc_w = {0.f, 0.f, 0.f, 0.f};
    f32x4 acc_n = {0.f, 0.f, 0.f, 0.f};

    FragU ones_col;
#pragma unroll
    for (int j = 0; j < 8; ++j) ones_col.s[j] = (m == 0) ? (short)0x3F80 : (short)0;

    int4 La0 = *reinterpret_cast<const int4*>(&L[off]);
    int4 La1 = *reinterpret_cast<const int4*>(&L[off + 4]);
    float4 Fa0 = *reinterpret_cast<const float4*>(&E[off]);
    float4 Fa1 = *reinterpret_cast<const float4*>(&E[off + 4]);
    int4 Lb0 = *reinterpret_cast<const int4*>(&L[off + 32]);
    int4 Lb1 = *reinterpret_cast<const int4*>(&L[off + 36]);
    float4 Fb0 = *reinterpret_cast<const float4*>(&E[off + 32]);
    float4 Fb1 = *reinterpret_cast<const float4*>(&E[off + 36]);

#pragma unroll
    for (int i = 0; i < 8; ++i) {
        int4 cl0, cl1; float4 cf0, cf1;
        if (i & 1) { cl0 = Lb0; cl1 = Lb1; cf0 = Fb0; cf1 = Fb1; }
        else       { cl0 = La0; cl1 = La1; cf0 = Fa0; cf1 = Fa1; }
        if (i < 6) {
            int noff = off + (i + 2) * 32;
            if (i & 1) {
                Lb0 = *reinterpret_cast<const int4*>(&L[noff]);
                Lb1 = *reinterpret_cast<const int4*>(&L[noff + 4]);
                Fb0 = *reinterpret_cast<const float4*>(&E[noff]);
                Fb1 = *reinterpret_cast<const float4*>(&E[noff + 4]);
            } else {
                La0 = *reinterpret_cast<const int4*>(&L[noff]);
                La1 = *reinterpret_cast<const int4*>(&L[noff + 4]);
                Fa0 = *reinterpret_cast<const float4*>(&E[noff]);
                Fa1 = *reinterpret_cast<const float4*>(&E[noff + 4]);
            }
        }
        int s0 = i * 8 + quad * 2;
        unsigned ebA = (unsigned)__shfl((int)eb_own, s0, 64);
        unsigned ebB = (unsigned)__shfl((int)eb_own, s0 + 1, 64);
        unsigned eb = (ebA & 0xF) | ((ebB & 0xF) << 4);

        int ls[8] = {cl0.x, cl0.y, cl0.z, cl0.w, cl1.x, cl1.y, cl1.z, cl1.w};
        float fs[8] = {cf0.x, cf0.y, cf0.z, cf0.w, cf1.x, cf1.y, cf1.z, cf1.w};

        FragU a, a2, bf;
#pragma unroll
        for (int j = 0; j < 8; ++j) {
            short w = ((eb >> j) & 1) ? (short)0x4120 : (short)0x3F80;   // 10.0 : 1.0
            bool hit = (ls[j] == m + 1);
            a.s[j]  = hit ? w : (short)0;
            a2.s[j] = hit ? (short)0x3F80 : (short)0;
            bf.s[j] = f2bf(fs[j]);
        }
        acc_c = __builtin_amdgcn_mfma_f32_16x16x32_bf16(a.v, bf.v, acc_c, 0, 0, 0);
        acc_w = __builtin_amdgcn_mfma_f32_16x16x32_bf16(a.v, ones_col.v, acc_w, 0, 0, 0);
        acc_n = __builtin_amdgcn_mfma_f32_16x16x32_bf16(a2.v, ones_col.v, acc_n, 0, 0, 0);
    }

    for (int i = tid; i < 288; i += 256) cacc[i] = 0.f;
    __syncthreads();
#pragma unroll
    for (int rr = 0; rr < 4; ++rr)
        atomicAdd(&cacc[(quad * 4 + rr) * 16 + m], acc_c[rr]);
    if (m == 0) {
#pragma unroll
        for (int rr = 0; rr < 4; ++rr) {
            atomicAdd(&cacc[256 + quad * 4 + rr], acc_w[rr]);
            atomicAdd(&cacc[272 + quad * 4 + rr], acc_n[rr]);
        }
    }
    __syncthreads();
    {
        float* segbase = acc + OFF_SEGM + mir * 612 + b * 306;
        atomicAdd(&segbase[16 + tid], cacc[tid]);
        if (tid < 16) atomicAdd(&segbase[272 + 1 + tid], cacc[256 + tid]);
        else if (tid < 32) atomicAdd(&segbase[289 + 1 + (tid - 16)], cacc[256 + tid]);
    }
    __syncthreads();   // protect cacc before next task re-zeroes
}

// ce half-tile h in [0,2048): 512 voxels, 2 per thread (float2 loads)
__device__ void ce_half(const float* __restrict__ logits, const int* __restrict__ cls,
                        float* __restrict__ acc, int b, int h, float* sh) {
    int tid = threadIdx.x;
    int mir = h & (MIR - 1);
    int vb = h * 512 + tid * 2;
    const float* lg = logits + (size_t)b * 8 * DHW;
    const int* cl = cls + (size_t)b * DHW;

    float2 xc[8];
#pragma unroll
    for (int c = 0; c < 8; ++c)
        xc[c] = *reinterpret_cast<const float2*>(&lg[(size_t)c * DHW + vb]);
    int2 t2 = *reinterpret_cast<const int2*>(&cl[vb]);
    int tt[2] = {t2.x, t2.y};

    float nll = 0.f, cardp[8], inter[8], cardg[8];
#pragma unroll
    for (int c = 0; c < 8; ++c) { cardp[c] = 0.f; inter[c] = 0.f; cardg[c] = 0.f; }

#pragma unroll
    for (int j = 0; j < 2; ++j) {
        float x[8];
#pragma unroll
        for (int c = 0; c < 8; ++c) x[c] = j ? xc[c].y : xc[c].x;
        int tgt = tt[j];
        bool valid = (tgt != -100);
        float mx = x[0];
#pragma unroll
        for (int c = 1; c < 8; ++c) mx = fmaxf(mx, x[c]);
        float e[8], s = 0.f;
#pragma unroll
        for (int c = 0; c < 8; ++c) { e[c] = __expf(x[c] - mx); s += e[c]; }
        float inv = 1.0f / s;
        float lse = __logf(s);
        if (valid) {
#pragma unroll
            for (int c = 0; c < 8; ++c) {
                float p = e[c] * inv;
                cardp[c] += p;
                if (tgt == c) { inter[c] += p; cardg[c] += 1.f; nll += mx + lse - x[c]; }
            }
        }
    }

    if (tid < 25) sh[tid] = 0.f;
    __syncthreads();
    int lane = tid & 63;
    float vals[25];
    vals[0] = nll;
#pragma unroll
    for (int c = 0; c < 8; ++c) { vals[1 + c] = cardp[c]; vals[9 + c] = inter[c]; vals[17 + c] = cardg[c]; }
#pragma unroll
    for (int i = 0; i < 25; ++i) {
        float r = vals[i];
#pragma unroll
        for (int off = 32; off > 0; off >>= 1) r += __shfl_down(r, off, 64);
        if (lane == 0) atomicAdd(&sh[i], r);
    }
    __syncthreads();
    if (tid < 25) {
        int dst;
        if (tid == 0) dst = 0;
        else if (tid < 9) dst = 1 + b * 8 + (tid - 1);
        else if (tid < 17) dst = 17 + b * 8 + (tid - 9);
        else dst = 33 + b * 8 + (tid - 17);
        atomicAdd(&acc[OFF_CEM + mir * 49 + dst], sh[tid]);
    }
    __syncthreads();
}

// pull task t in [0,2048): b=t&1 (== blockIdx parity), blk=t>>1; ctr = 272-float centers in LDS
__device__ void pull_task(const float* __restrict__ embed, const int* __restrict__ labels,
                          float* __restrict__ acc, int t, const float* __restrict__ ctr, float* ps) {
    int tid = threadIdx.x;
    int b = t & 1;
    int blk = t >> 1;
    int wv = tid >> 6;
    for (int i = tid; i < 80; i += 256) ps[i] = 0.f;
    __syncthreads();

    const int* L = labels + (size_t)b * DHW;
    const float* E = embed + (size_t)b * 16 * DHW;
    int vb = (blk * 256 + tid) * 4;

    int4 l4 = *reinterpret_cast<const int4*>(&L[vb]);
    int l[4] = {l4.x, l4.y, l4.z, l4.w};
    unsigned eb;
    {
        const unsigned char* EB = (const unsigned char*)acc + OFF_EDGE_BYTES + ((size_t)b << 18);
        eb = EB[blk * 256 + tid];
    }

    float d2a[4] = {0.f, 0.f, 0.f, 0.f};
#pragma unroll
    for (int q = 0; q < 4; ++q) {
        float4 e0 = *reinterpret_cast<const float4*>(&E[(size_t)(4 * q + 0) * DHW + vb]);
        float4 e1 = *reinterpret_cast<const float4*>(&E[(size_t)(4 * q + 1) * DHW + vb]);
        float4 e2 = *reinterpret_cast<const float4*>(&E[(size_t)(4 * q + 2) * DHW + vb]);
        float4 e3 = *reinterpret_cast<const float4*>(&E[(size_t)(4 * q + 3) * DHW + vb]);
#pragma unroll
        for (int j = 0; j < 4; ++j) {
            if (l[j] != 0) {
                float4 cv = *reinterpret_cast<const float4*>(&ctr[l[j] * 16 + q * 4]);
                float d0 = ((const float*)&e0)[j] - cv.x;
                float d1 = ((const float*)&e1)[j] - cv.y;
                float d2 = ((const float*)&e2)[j] - cv.z;
                float d3 = ((const float*)&e3)[j] - cv.w;
                d2a[j] += d0 * d0 + d1 * d1 + d2 * d2 + d3 * d3;
            }
        }
    }

#pragma unroll
    for (int j = 0; j < 4; ++j) {
        if (l[j] != 0) {
            float w = ((eb >> j) & 1) ? 10.f : 1.f;
            float d = fmaxf(sqrtf(d2a[j]) - 0.5f, 0.f);
            atomicAdd(&ps[wv * 20 + l[j]], d * d * w);
        }
    }
    __syncthreads();
    if (tid >= 1 && tid < 17) {
        float v = ps[tid] + ps[20 + tid] + ps[40 + tid] + ps[60 + tid];
        int mir = blk & (MIR - 1);
        if (v != 0.f) atomicAdd(&acc[OFF_PULLM + mir * 34 + b * 17 + tid], v);
    }
    __syncthreads();
}

// finalize (run by a single block)
__device__ void finalize_dev(const float* __restrict__ acc, float* __restrict__ out) {
    __shared__ float s_ce[49], s_pl[34];
    __shared__ float sh_push[2], sh_norm[2], sh_pull[2], sh_npres[2];
    int tid = threadIdx.x;
    if (tid < 49) {
        float s = 0.f;
        for (int mv = 0; mv < MIR; ++mv) s += acc[OFF_CEM + mv * 49 + tid];
        s_ce[tid] = s;
    }
    if (tid >= 64 && tid < 98) {
        int j = tid - 64;
        float s = 0.f;
        for (int mv = 0; mv < MIR; ++mv) s += acc[OFF_PULLM + mv * 34 + j];
        s_pl[j] = s;
    }
    if (tid < 2) { sh_push[tid] = 0.f; sh_norm[tid] = 0.f; sh_pull[tid] = 0.f; sh_npres[tid] = 0.f; }
    __syncthreads();

    if (tid < 32) {
        int b = tid >> 4, k = (tid & 15) + 1;
        float cnt = acc[OFF_CNT + b * 17 + k];
        if (cnt > 0.f) {
            atomicAdd(&sh_npres[b], 1.f);
            atomicAdd(&sh_pull[b], s_pl[b * 17 + k] / fmaxf(cnt, 1.f));
            const float* c = &acc[OFF_CTR + (b * 17 + k) * 16];
            float n2 = 0.f;
            for (int i = 0; i < 16; ++i) n2 += c[i] * c[i];
            atomicAdd(&sh_norm[b], sqrtf(n2));
        }
    }
    for (int t = tid; t < 240; t += blockDim.x) {
        int b = t / 120, p = t % 120;
        int i = 1, rem = p;
        while (rem >= (16 - i)) { rem -= (16 - i); ++i; }
        int j = i + 1 + rem;
        bool pi = acc[OFF_CNT + b * 17 + i] > 0.f;
        bool pj = acc[OFF_CNT + b * 17 + j] > 0.f;
        if (pi && pj) {
            const float* ci = &acc[OFF_CTR + (b * 17 + i) * 16];
            const float* cj = &acc[OFF_CTR + (b * 17 + j) * 16];
            float d2 = 0.f;
            for (int c = 0; c < 16; ++c) { float dd = ci[c] - cj[c]; d2 += dd * dd; }
            float r = fmaxf(3.0f - sqrtf(d2), 0.f);
            atomicAdd(&sh_push[b], r * r);
        }
    }
    __syncthreads();
    if (tid == 0) {
        float nll = s_ce[0];
        float vcnt = 0.f;
        for (int i = 0; i < 16; ++i) vcnt += s_ce[33 + i];
        float ce = nll / fmaxf(vcnt, 1.f);
        float dsum = 0.f;
        for (int i = 0; i < 16; ++i) {
            float it = s_ce[17 + i], cp = s_ce[1 + i], cg = s_ce[33 + i];
            dsum += (2.f * it + 1e-5f) / (cp + cg + 1e-5f);
        }
        float dice = 1.f - dsum / 16.f;
        float lp = 0.f, lpu = 0.f, ln = 0.f, val = 0.f;
        for (int b = 0; b < 2; ++b) {
            float npres = sh_npres[b];
            lp += sh_pull[b];
            float npairs = npres * (npres - 1.f) * 0.5f;
            lpu += (npairs > 0.f) ? sh_push[b] / fmaxf(npairs, 1.f) : 0.f;
            ln += (npres > 0.f) ? sh_norm[b] / fmaxf(npres, 1.f) : 0.f;
            val += (npres > 0.f) ? 1.f : 0.f;
        }
        float n = fmaxf(val, 1.f);
        float ins = (1.0f * lp + 1.0f * lpu + 0.001f * ln) / n;
        float sem = ce + dice;
        out[0] = sem + ins;
        out[1] = sem;
        out[2] = ce;
        out[3] = dice;
        out[4] = ins;
    }
}

// ---------------- fused cooperative kernel ----------------
__global__ __launch_bounds__(256) void fused_kernel(const float* __restrict__ logits,
                                                    const float* __restrict__ embed,
                                                    const int* __restrict__ cls,
                                                    const int* __restrict__ labels,
                                                    float* __restrict__ acc,
                                                    float* __restrict__ out) {
    cg::grid_group grid = cg::this_grid();
    __shared__ float smem[400];
    int tid = threadIdx.x;
    int nb = gridDim.x;          // power of two, >= 256

    // S0: zero accumulators
    for (int i = blockIdx.x * 256 + tid; i < ACC_FLOATS; i += nb * 256) acc[i] = 0.f;
    grid.sync();

    // interval 1: seg (all 2048) + ce half-tiles b=0
    for (int t = blockIdx.x; t < 2048; t += nb) seg_task(embed, labels, acc, t, smem);
    for (int t = blockIdx.x; t < 2048; t += nb) ce_half(logits, cls, acc, 0, t, smem + 352);
    grid.sync();

    // interval 2: per-block centers (for my parity's batch), then pull + ce b=1
    {
        int b = blockIdx.x & 1;          // pull tasks t=blockIdx+k*nb all share this parity
        int k = 1 + (tid >> 4), c = tid & 15;
        float cn = 0.f, ws = 0.f;
        for (int mv = 0; mv < MIR; ++mv) {
            const float* segbase = acc + OFF_SEGM + mv * 612 + b * 306;
            cn += segbase[k * 16 + c];
            ws += segbase[272 + k];
        }
        float cv = cn / (ws + 1e-8f);
        smem[k * 16 + c] = cv;
        if (tid < 16) smem[tid] = 0.f;
        if (blockIdx.x < 2) {            // blocks 0,1 publish centers + counts for finalize
            acc[OFF_CTR + b * 272 + k * 16 + c] = cv;
            if (tid < 17) {
                float s = 0.f;
                for (int mv = 0; mv < MIR; ++mv)
                    s += acc[OFF_SEGM + mv * 612 + b * 306 + 289 + tid];
                acc[OFF_CNT + b * 17 + tid] = s;
            }
        }
        __syncthreads();
    }
    for (int t = blockIdx.x; t < 2048; t += nb) pull_task(embed, labels, acc, t, smem, smem + 288);
    for (int t = blockIdx.x; t < 2048; t += nb) ce_half(logits, cls, acc, 1, t, smem + 352);
    grid.sync();

    if (blockIdx.x == 0) finalize_dev(acc, out);
}

// ---------------- fallback path (round-2 kernels) ----------------
__global__ void zero_kernel(float* acc) {
    int i = blockIdx.x * 1024 + threadIdx.x;
    if (i < ACC_FLOATS) acc[i] = 0.0f;
}

__device__ void ce_role4(const float* __restrict__ logits, const int* __restrict__ cls,
                         float* __restrict__ acc, int b, int blk, float* sh) {
    int tid = threadIdx.x;
    int mir = blk & (MIR - 1);
    int vb = (blk * 256 + tid) * 4;
    const float* lg = logits + (size_t)b * 8 * DHW;
    const int* cl = cls + (size_t)b * DHW;
    float4 xc[8];
#pragma unroll
    for (int c = 0; c < 8; ++c)
        xc[c] = *reinterpret_cast<const float4*>(&lg[(size_t)c * DHW + vb]);
    int4 t4 = *reinterpret_cast<const int4*>(&cl[vb]);
    int tt[4] = {t4.x, t4.y, t4.z, t4.w};
    float nll = 0.f, cardp[8], inter[8], cardg[8];
#pragma unroll
    for (int c = 0; c < 8; ++c) { cardp[c] = 0.f; inter[c] = 0.f; cardg[c] = 0.f; }
#pragma unroll
    for (int j = 0; j < 4; ++j) {
        float x[8];
#pragma unroll
        for (int c = 0; c < 8; ++c) x[c] = ((const float*)&xc[c])[j];
        int t = tt[j];
        bool valid = (t != -100);
        float mx = x[0];
#pragma unroll
        for (int c = 1; c < 8; ++c) mx = fmaxf(mx, x[c]);
        float e[8], s = 0.f;
#pragma unroll
        for (int c = 0; c < 8; ++c) { e[c] = __expf(x[c] - mx); s += e[c]; }
        float inv = 1.0f / s;
        float lse = __logf(s);
        if (valid) {
#pragma unroll
            for (int c = 0; c < 8; ++c) {
                float p = e[c] * inv;
                cardp[c] += p;
                if (t == c) { inter[c] += p; cardg[c] += 1.f; nll += mx + lse - x[c]; }
            }
        }
    }
    if (tid < 25) sh[tid] = 0.f;
    __syncthreads();
    int lane = tid & 63;
    float vals[25];
    vals[0] = nll;
#pragma unroll
    for (int c = 0; c < 8; ++c) { vals[1 + c] = cardp[c]; vals[9 + c] = inter[c]; vals[17 + c] = cardg[c]; }
#pragma unroll
    for (int i = 0; i < 25; ++i) {
        float r = vals[i];
#pragma unroll
        for (int off = 32; off > 0; off >>= 1) r += __shfl_down(r, off, 64);
        if (lane == 0) atomicAdd(&sh[i], r);
    }
    __syncthreads();
    if (tid < 25) {
        int dst;
        if (tid == 0) dst = 0;
        else if (tid < 9) dst = 1 + b * 8 + (tid - 1);
        else if (tid < 17) dst = 17 + b * 8 + (tid - 9);
        else dst = 33 + b * 8 + (tid - 17);
        atomicAdd(&acc[OFF_CEM + mir * 49 + dst], sh[tid]);
    }
}

__global__ __launch_bounds__(256) void phaseA_kernel(const float* __restrict__ logits,
                                                     const float* __restrict__ embed,
                                                     const int* __restrict__ cls,
                                                     const int* __restrict__ labels,
                                                     float* __restrict__ acc) {
    __shared__ float smem[352];
    int x = blockIdx.x;
    int g = x / 11, r = x % 11;
    if (r >= 8) {
        int ce_idx = g * 3 + (r - 8);
        int b = (ce_idx >= 384) ? 1 : 0;
        ce_role4(logits, cls, acc, b, ce_idx - b * 384, smem);
        return;
    }
    seg_task(embed, labels, acc, g * 8 + r, smem);
}

__global__ __launch_bounds__(1024) void centers_kernel(float* acc) {
    int tid = threadIdx.x;
    if (tid < 544) {
        int b = tid / 272, r = tid % 272;
        int k = r >> 4;
        float cn = 0.f, ws = 0.f;
        for (int mv = 0; mv < MIR; ++mv) {
            const float* segbase = acc + OFF_SEGM + mv * 612 + b * 306;
            if (r >= 16) cn += segbase[r];
            ws += segbase[272 + k];
        }
        acc[OFF_CTR + tid] = (r >= 16) ? cn / (ws + 1e-8f) : 0.f;
    } else if (tid < 578) {
        int j = tid - 544;
        int b = j / 17, k = j % 17;
        float s = 0.f;
        for (int mv = 0; mv < MIR; ++mv)
            s += acc[OFF_SEGM + mv * 612 + b * 306 + 289 + k];
        acc[OFF_CNT + j] = s;
    }
}

__global__ __launch_bounds__(256) void phaseB_kernel(const float* __restrict__ logits,
                                                     const float* __restrict__ embed,
                                                     const int* __restrict__ cls,
                                                     const int* __restrict__ labels,
                                                     float* __restrict__ acc) {
    __shared__ float smem[352];
    int x = blockIdx.x;
    int g = x / 13, r = x % 13;
    int tid = threadIdx.x;
    if (r >= 8) {
        int ce_idx = g * 5 + (r - 8);
        int b = (ce_idx >= 640) ? 1 : 0;
        ce_role4(logits, cls, acc, b, 384 + (ce_idx - b * 640), smem);
        return;
    }
    int t = g * 8 + r;
    int b = t & 1;
    float* ctr = smem;
    for (int i = tid; i < 272; i += 256) ctr[i] = acc[OFF_CTR + b * 272 + i];
    __syncthreads();
    pull_task(embed, labels, acc, t, ctr, smem + 288);
}

__global__ __launch_bounds__(256) void finalize_kernel(const float* __restrict__ acc, float* __restrict__ out) {
    finalize_dev(acc, out);
}

extern "C" void kernel_launch(void* const* d_in, const int* in_sizes, int n_in,
                              void* d_out, int out_size, void* d_ws, size_t ws_size,
                              hipStream_t stream) {
    const float* sem = (const float*)d_in[0];
    const float* emb = (const float*)d_in[1];
    const int* cls = (const int*)d_in[2];
    const int* lab = (const int*)d_in[3];
    float* out = (float*)d_out;
    float* acc = (float*)d_ws;

    static int g_grid = -1;
    if (g_grid < 0) {
        int nb = 0;
        if (hipOccupancyMaxActiveBlocksPerMultiprocessor(&nb, fused_kernel, 256, 0) == hipSuccess && nb >= 1) {
            hipDeviceProp_t prop;
            int dev = 0;
            hipGetDevice(&dev);
            if (hipGetDeviceProperties(&prop, dev) == hipSuccess) {
                long cap = (long)nb * prop.multiProcessorCount;
                int g = 2048;
                while (g > 256 && g > cap) g >>= 1;
                g_grid = (cap >= 256) ? g : 0;
            } else g_grid = 0;
        } else g_grid = 0;
    }

    bool done = false;
    if (g_grid > 0) {
        void* args[] = {(void*)&sem, (void*)&emb, (void*)&cls, (void*)&lab, (void*)&acc, (void*)&out};
        if (hipLaunchCooperativeKernel(fused_kernel, dim3(g_grid), dim3(256), args, 0, stream) == hipSuccess)
            done = true;
    }
    if (!done) {   // fallback: round-2 5-kernel path
        hipLaunchKernelGGL(zero_kernel, dim3(23), dim3(1024), 0, stream, acc);
        hipLaunchKernelGGL(phaseA_kernel, dim3(2816), dim3(256), 0, stream, sem, emb, cls, lab, acc);
        hipLaunchKernelGGL(centers_kernel, dim3(1), dim3(1024), 0, stream, acc);
        hipLaunchKernelGGL(phaseB_kernel, dim3(3328), dim3(256), 0, stream, sem, emb, cls, lab, acc);
        hipLaunchKernelGGL(finalize_kernel, dim3(1), dim3(256), 0, stream, acc, out);
    }
}

// Round 4
// 306.636 us; speedup vs baseline: 1.7309x; 1.7309x over previous
//
#include <hip/hip_runtime.h>

#define DHW (64*128*128)
#define MIR 32

// accumulator layout in d_ws (floats)
#define OFF_CEM   0        // [MIR][49]: nll, cardp[2][8], inter[2][8], cardg[2][8]
#define OFF_SEGM  1568     // [MIR][2][306]: cnum[17][16] (16..271), wsum[17] (272..288), cnt[17] (289..305)
#define OFF_PULLM 21152    // [MIR][2][17]
#define OFF_CTR   22240    // [2][17][16]
#define OFF_CNT   22784    // [2][17]
#define ACC_FLOATS 22818
#define OFF_EDGE_BYTES 92160   // byte offset into ws: 2 * DHW/4 bytes = 512 KiB edge-bit cache

typedef __bf16 bf16x8 __attribute__((ext_vector_type(8)));
typedef float f32x4 __attribute__((ext_vector_type(4)));
union FragU { short s[8]; bf16x8 v; };

__device__ inline short f2bf(float f) {   // RTNE float->bf16
    union { float f; unsigned u; } v; v.f = f;
    unsigned r = v.u + 0x7FFF + ((v.u >> 16) & 1);
    return (short)(r >> 16);
}

__global__ void zero_kernel(float* acc) {
    int i = blockIdx.x * 1024 + threadIdx.x;
    if (i < ACC_FLOATS) acc[i] = 0.0f;
}

// ---------------- ce_dice role (1024-voxel tile) ----------------
__device__ void ce_role(const float* __restrict__ logits, const int* __restrict__ cls,
                        float* __restrict__ acc, int b, int blk, float* sh) {
    int tid = threadIdx.x;
    int mir = blk & (MIR - 1);
    int vb = (blk * 256 + tid) * 4;
    const float* lg = logits + (size_t)b * 8 * DHW;
    const int* cl = cls + (size_t)b * DHW;

    float4 xc[8];
#pragma unroll
    for (int c = 0; c < 8; ++c)
        xc[c] = *reinterpret_cast<const float4*>(&lg[(size_t)c * DHW + vb]);
    int4 t4 = *reinterpret_cast<const int4*>(&cl[vb]);
    int tt[4] = {t4.x, t4.y, t4.z, t4.w};

    float nll = 0.f, cardp[8], inter[8], cardg[8];
#pragma unroll
    for (int c = 0; c < 8; ++c) { cardp[c] = 0.f; inter[c] = 0.f; cardg[c] = 0.f; }

#pragma unroll
    for (int j = 0; j < 4; ++j) {
        float x[8];
#pragma unroll
        for (int c = 0; c < 8; ++c) x[c] = ((const float*)&xc[c])[j];
        int t = tt[j];
        bool valid = (t != -100);
        float mx = x[0];
#pragma unroll
        for (int c = 1; c < 8; ++c) mx = fmaxf(mx, x[c]);
        float e[8], s = 0.f;
#pragma unroll
        for (int c = 0; c < 8; ++c) { e[c] = __expf(x[c] - mx); s += e[c]; }
        float inv = 1.0f / s;
        float lse = __logf(s);
        if (valid) {
#pragma unroll
            for (int c = 0; c < 8; ++c) {
                float p = e[c] * inv;
                cardp[c] += p;
                if (t == c) { inter[c] += p; cardg[c] += 1.f; nll += mx + lse - x[c]; }
            }
        }
    }

    if (tid < 25) sh[tid] = 0.f;
    __syncthreads();
    int lane = tid & 63;
    float vals[25];
    vals[0] = nll;
#pragma unroll
    for (int c = 0; c < 8; ++c) { vals[1 + c] = cardp[c]; vals[9 + c] = inter[c]; vals[17 + c] = cardg[c]; }
#pragma unroll
    for (int i = 0; i < 25; ++i) {
        float r = vals[i];
#pragma unroll
        for (int off = 32; off > 0; off >>= 1) r += __shfl_down(r, off, 64);
        if (lane == 0) atomicAdd(&sh[i], r);
    }
    __syncthreads();
    if (tid < 25) {
        int dst;
        if (tid == 0) dst = 0;
        else if (tid < 9) dst = 1 + b * 8 + (tid - 1);
        else if (tid < 17) dst = 17 + b * 8 + (tid - 9);
        else dst = 33 + b * 8 + (tid - 17);
        atomicAdd(&acc[OFF_CEM + mir * 49 + dst], sh[tid]);
    }
}

// ---------------- phase A: seg (LDS-staged labels) + ce ----------------
__global__ __launch_bounds__(256) void phaseA_kernel(const float* __restrict__ logits,
                                                     const float* __restrict__ embed,
                                                     const int* __restrict__ cls,
                                                     const int* __restrict__ labels,
                                                     float* __restrict__ acc) {
    __shared__ int s_tile[3840];            // 3 z * 10 y-rows * 128 x labels
    __shared__ unsigned char s_eb[256];     // edge bits, 1 byte per 4 voxels
    __shared__ float s_cacc[288];
    int x = blockIdx.x;
    int g = x / 11, r3 = x % 11;
    int tid = threadIdx.x;

    if (r3 >= 8) {              // ce role: 3 per group of 11 -> 768 tiles
        int ce_idx = g * 3 + (r3 - 8);       // [0,768)
        int b = (ce_idx >= 384) ? 1 : 0;
        int blk = ce_idx - b * 384;          // [0,384)
        ce_role(logits, cls, acc, b, blk, s_cacc);
        return;
    }
    // seg role
    int seg_idx = g * 8 + r3;   // [0,2048)
    int b = seg_idx & 1;
    int blk = seg_idx >> 1;     // [0,1024)
    int mir = blk & (MIR - 1);
    int lane = tid & 63;
    int wv = tid >> 6;
    int m = lane & 15;          // A-row (label m+1) / B-col (channel m)
    int quad = lane >> 4;

    const int* L = labels + (size_t)b * DHW;
    const float* E = embed + (size_t)b * 16 * DHW + (size_t)m * DHW;

    int vb0 = blk * 1024;
    int z0 = vb0 >> 14;
    int y0 = (vb0 >> 7) & 127;

    // stage 30 label rows (z0-1..z0+1 x y0-1..y0+8, edge-clamped) into LDS
    for (int idx = tid; idx < 960; idx += 256) {
        int row = idx >> 5, col = idx & 31;       // col in int4 units
        int zi = row / 10, ri = row - zi * 10;
        int zz = min(max(z0 + zi - 1, 0), 63);
        int yy = min(max(y0 + ri - 1, 0), 127);
        reinterpret_cast<int4*>(s_tile)[row * 32 + col] =
            *reinterpret_cast<const int4*>(&L[(zz << 14) + (yy << 7) + col * 4]);
    }
    __syncthreads();

    // edge bits for own 4 voxels (voxel base tid*4 within the 1024) from LDS
    {
        int p = tid * 4;
        int xx = p & 127, lr = p >> 7;            // local row 0..7 -> tile ri = lr+1
        int xm = max(xx - 1, 0), xp = min(xx + 4, 127);
        const int* crow = &s_tile[(10 + lr + 1) * 128];
        int4 c; c.x = crow[xx]; c.y = crow[xx + 1]; c.z = crow[xx + 2]; c.w = crow[xx + 3];
        unsigned b0 = 0, b1 = 0, b2 = 0, b3 = 0;
#pragma unroll
        for (int zi = 0; zi < 3; ++zi) {
#pragma unroll
            for (int dy = 0; dy < 3; ++dy) {
                const int* row = &s_tile[(zi * 10 + lr + dy) * 128];
                int rx = row[xx], ry = row[xx + 1], rz = row[xx + 2], rw = row[xx + 3];
                int rm = row[xm], rp = row[xp];
                b0 |= (rm != c.x) | (rx != c.x) | (ry != c.x);
                b1 |= (rx != c.y) | (ry != c.y) | (rz != c.y);
                b2 |= (ry != c.z) | (rz != c.z) | (rw != c.z);
                b3 |= (rz != c.w) | (rw != c.w) | (rp != c.w);
            }
        }
        unsigned eb_own = b0 | (b1 << 1) | (b2 << 2) | (b3 << 3);
        s_eb[tid] = (unsigned char)eb_own;
        unsigned char* EB = (unsigned char*)acc + OFF_EDGE_BYTES + ((size_t)b << 18);
        EB[blk * 256 + tid] = (unsigned char)eb_own;
    }
    __syncthreads();

    int lo0 = wv * 256 + quad * 8;   // local offset of this lane's first 8-voxel chunk

    f32x4 acc_c = {0.f, 0.f, 0.f, 0.f};
    f32x4 acc_w = {0.f, 0.f, 0.f, 0.f};
    f32x4 acc_n = {0.f, 0.f, 0.f, 0.f};

    FragU ones_col;
#pragma unroll
    for (int j = 0; j < 8; ++j) ones_col.s[j] = (m == 0) ? (short)0x3F80 : (short)0;

    // depth-2 prefetch on the embed stream only (labels come from LDS now)
    int goff = vb0 + lo0;
    float4 Fa0 = *reinterpret_cast<const float4*>(&E[goff]);
    float4 Fa1 = *reinterpret_cast<const float4*>(&E[goff + 4]);
    float4 Fb0 = *reinterpret_cast<const float4*>(&E[goff + 32]);
    float4 Fb1 = *reinterpret_cast<const float4*>(&E[goff + 36]);

#pragma unroll
    for (int i = 0; i < 8; ++i) {
        float4 cf0, cf1;
        if (i & 1) { cf0 = Fb0; cf1 = Fb1; }
        else       { cf0 = Fa0; cf1 = Fa1; }
        if (i < 6) {
            int noff = goff + (i + 2) * 32;
            if (i & 1) {
                Fb0 = *reinterpret_cast<const float4*>(&E[noff]);
                Fb1 = *reinterpret_cast<const float4*>(&E[noff + 4]);
            } else {
                Fa0 = *reinterpret_cast<const float4*>(&E[noff]);
                Fa1 = *reinterpret_cast<const float4*>(&E[noff + 4]);
            }
        }
        // labels for this chunk from the LDS tile (central z, rows 1..8)
        int lo = lo0 + i * 32;
        const int* rowp = &s_tile[(10 + (lo >> 7) + 1) * 128 + (lo & 127)];
        // edge bits for the 8 voxels of this K-slice
        int s0 = i * 8 + quad * 2;
        unsigned short u = *reinterpret_cast<const unsigned short*>(&s_eb[wv * 64 + s0]);
        unsigned eb = (u & 0xF) | ((u >> 4) & 0xF0);

        FragU a, a2, bf;
#pragma unroll
        for (int j = 0; j < 8; ++j) {
            short w = ((eb >> j) & 1) ? (short)0x4120 : (short)0x3F80;   // 10.0 : 1.0
            bool hit = (rowp[j] == m + 1);
            a.s[j]  = hit ? w : (short)0;
            a2.s[j] = hit ? (short)0x3F80 : (short)0;
            float fv = (j < 4) ? ((const float*)&cf0)[j] : ((const float*)&cf1)[j - 4];
            bf.s[j] = f2bf(fv);
        }
        acc_c = __builtin_amdgcn_mfma_f32_16x16x32_bf16(a.v, bf.v, acc_c, 0, 0, 0);
        acc_w = __builtin_amdgcn_mfma_f32_16x16x32_bf16(a.v, ones_col.v, acc_w, 0, 0, 0);
        acc_n = __builtin_amdgcn_mfma_f32_16x16x32_bf16(a2.v, ones_col.v, acc_n, 0, 0, 0);
    }

    for (int i = tid; i < 288; i += 256) s_cacc[i] = 0.f;
    __syncthreads();
#pragma unroll
    for (int rr = 0; rr < 4; ++rr)
        atomicAdd(&s_cacc[(quad * 4 + rr) * 16 + m], acc_c[rr]);
    if (m == 0) {
#pragma unroll
        for (int rr = 0; rr < 4; ++rr) {
            atomicAdd(&s_cacc[256 + quad * 4 + rr], acc_w[rr]);
            atomicAdd(&s_cacc[272 + quad * 4 + rr], acc_n[rr]);
        }
    }
    __syncthreads();
    {
        float* segbase = acc + OFF_SEGM + mir * 612 + b * 306;
        atomicAdd(&segbase[16 + tid], s_cacc[tid]);
        if (tid < 16) atomicAdd(&segbase[272 + 1 + tid], s_cacc[256 + tid]);
        else if (tid < 32) atomicAdd(&segbase[289 + 1 + (tid - 16)], s_cacc[256 + tid]);
    }
}

// ---------------- centers: sum mirrors, divide ----------------
__global__ __launch_bounds__(1024) void centers_kernel(float* acc) {
    int tid = threadIdx.x;
    if (tid < 544) {
        int b = tid / 272, r = tid % 272;       // r = k*16+c
        int k = r >> 4;
        float cn = 0.f, ws = 0.f;
        for (int mv = 0; mv < MIR; ++mv) {
            const float* segbase = acc + OFF_SEGM + mv * 612 + b * 306;
            if (r >= 16) cn += segbase[r];
            ws += segbase[272 + k];
        }
        acc[OFF_CTR + tid] = (r >= 16) ? cn / (ws + 1e-8f) : 0.f;
    } else if (tid < 578) {
        int j = tid - 544;                       // b*17+k
        int b = j / 17, k = j % 17;
        float s = 0.f;
        for (int mv = 0; mv < MIR; ++mv)
            s += acc[OFF_SEGM + mv * 612 + b * 306 + 289 + k];
        acc[OFF_CNT + j] = s;
    }
}

// ---------------- phase B: pull + ce ----------------
__global__ __launch_bounds__(256) void phaseB_kernel(const float* __restrict__ logits,
                                                     const float* __restrict__ embed,
                                                     const int* __restrict__ cls,
                                                     const int* __restrict__ labels,
                                                     float* __restrict__ acc) {
    __shared__ float smem[352];
    int x = blockIdx.x;
    int g = x / 13, r3 = x % 13;
    int tid = threadIdx.x;

    if (r3 >= 8) {              // ce role: 5 per group of 13 -> 1280 tiles
        int ce_idx = g * 5 + (r3 - 8);       // [0,1280)
        int b = (ce_idx >= 640) ? 1 : 0;
        int blk = 384 + (ce_idx - b * 640);  // [384,1024)
        ce_role(logits, cls, acc, b, blk, smem);
        return;
    }
    // pull role
    int pull_idx = g * 8 + r3;  // [0,2048)
    int b = pull_idx & 1;
    int blk = pull_idx >> 1;    // [0,1024)
    int wv = tid >> 6;
    float* ctr = smem;          // 272
    float* ps = smem + 272;     // 80
    for (int i = tid; i < 272; i += 256) ctr[i] = acc[OFF_CTR + b * 272 + i];
    for (int i = tid; i < 80; i += 256) ps[i] = 0.f;
    __syncthreads();

    const int* L = labels + (size_t)b * DHW;
    const float* E = embed + (size_t)b * 16 * DHW;
    int vb = (blk * 256 + tid) * 4;

    int4 l4 = *reinterpret_cast<const int4*>(&L[vb]);
    int l[4] = {l4.x, l4.y, l4.z, l4.w};
    unsigned eb;
    {
        const unsigned char* EB = (const unsigned char*)acc + OFF_EDGE_BYTES + ((size_t)b << 18);
        eb = EB[blk * 256 + tid];
    }

    // hoist all 16 embed loads (independent, max MLP)
    float4 ev[16];
#pragma unroll
    for (int c = 0; c < 16; ++c)
        ev[c] = *reinterpret_cast<const float4*>(&E[(size_t)c * DHW + vb]);

    float d2a[4] = {0.f, 0.f, 0.f, 0.f};
#pragma unroll
    for (int q = 0; q < 4; ++q) {
#pragma unroll
        for (int j = 0; j < 4; ++j) {
            if (l[j] != 0) {
                float4 cv = *reinterpret_cast<const float4*>(&ctr[l[j] * 16 + q * 4]);
                float d0 = ((const float*)&ev[4 * q + 0])[j] - cv.x;
                float d1 = ((const float*)&ev[4 * q + 1])[j] - cv.y;
                float d2 = ((const float*)&ev[4 * q + 2])[j] - cv.z;
                float d3 = ((const float*)&ev[4 * q + 3])[j] - cv.w;
                d2a[j] += d0 * d0 + d1 * d1 + d2 * d2 + d3 * d3;
            }
        }
    }

#pragma unroll
    for (int j = 0; j < 4; ++j) {
        if (l[j] != 0) {
            float w = ((eb >> j) & 1) ? 10.f : 1.f;
            float d = fmaxf(sqrtf(d2a[j]) - 0.5f, 0.f);
            atomicAdd(&ps[wv * 20 + l[j]], d * d * w);
        }
    }
    __syncthreads();
    if (tid >= 1 && tid < 17) {
        float v = ps[tid] + ps[20 + tid] + ps[40 + tid] + ps[60 + tid];
        int mir = blk & (MIR - 1);
        if (v != 0.f) atomicAdd(&acc[OFF_PULLM + mir * 34 + b * 17 + tid], v);
    }
}

// ---------------- finalize ----------------
__global__ __launch_bounds__(256) void finalize_kernel(const float* __restrict__ acc, float* __restrict__ out) {
    __shared__ float s_ce[49], s_pl[34];
    __shared__ float sh_push[2], sh_norm[2], sh_pull[2], sh_npres[2];
    int tid = threadIdx.x;
    if (tid < 49) {
        float s = 0.f;
        for (int mv = 0; mv < MIR; ++mv) s += acc[OFF_CEM + mv * 49 + tid];
        s_ce[tid] = s;
    }
    if (tid >= 64 && tid < 98) {
        int j = tid - 64;
        float s = 0.f;
        for (int mv = 0; mv < MIR; ++mv) s += acc[OFF_PULLM + mv * 34 + j];
        s_pl[j] = s;
    }
    if (tid < 2) { sh_push[tid] = 0.f; sh_norm[tid] = 0.f; sh_pull[tid] = 0.f; sh_npres[tid] = 0.f; }
    __syncthreads();

    if (tid < 32) {
        int b = tid >> 4, k = (tid & 15) + 1;
        float cnt = acc[OFF_CNT + b * 17 + k];
        if (cnt > 0.f) {
            atomicAdd(&sh_npres[b], 1.f);
            atomicAdd(&sh_pull[b], s_pl[b * 17 + k] / fmaxf(cnt, 1.f));
            const float* c = &acc[OFF_CTR + (b * 17 + k) * 16];
            float n2 = 0.f;
            for (int i = 0; i < 16; ++i) n2 += c[i] * c[i];
            atomicAdd(&sh_norm[b], sqrtf(n2));
        }
    }
    for (int t = tid; t < 240; t += blockDim.x) {
        int b = t / 120, p = t % 120;
        int i = 1, rem = p;
        while (rem >= (16 - i)) { rem -= (16 - i); ++i; }
        int j = i + 1 + rem;
        bool pi = acc[OFF_CNT + b * 17 + i] > 0.f;
        bool pj = acc[OFF_CNT + b * 17 + j] > 0.f;
        if (pi && pj) {
            const float* ci = &acc[OFF_CTR + (b * 17 + i) * 16];
            const float* cj = &acc[OFF_CTR + (b * 17 + j) * 16];
            float d2 = 0.f;
            for (int c = 0; c < 16; ++c) { float dd = ci[c] - cj[c]; d2 += dd * dd; }
            float r = fmaxf(3.0f - sqrtf(d2), 0.f);
            atomicAdd(&sh_push[b], r * r);
        }
    }
    __syncthreads();
    if (tid == 0) {
        float nll = s_ce[0];
        float vcnt = 0.f;
        for (int i = 0; i < 16; ++i) vcnt += s_ce[33 + i];
        float ce = nll / fmaxf(vcnt, 1.f);
        float dsum = 0.f;
        for (int i = 0; i < 16; ++i) {
            float it = s_ce[17 + i], cp = s_ce[1 + i], cg = s_ce[33 + i];
            dsum += (2.f * it + 1e-5f) / (cp + cg + 1e-5f);
        }
        float dice = 1.f - dsum / 16.f;
        float lp = 0.f, lpu = 0.f, ln = 0.f, val = 0.f;
        for (int b = 0; b < 2; ++b) {
            float npres = sh_npres[b];
            lp += sh_pull[b];
            float npairs = npres * (npres - 1.f) * 0.5f;
            lpu += (npairs > 0.f) ? sh_push[b] / fmaxf(npairs, 1.f) : 0.f;
            ln += (npres > 0.f) ? sh_norm[b] / fmaxf(npres, 1.f) : 0.f;
            val += (npres > 0.f) ? 1.f : 0.f;
        }
        float n = fmaxf(val, 1.f);
        float ins = (1.0f * lp + 1.0f * lpu + 0.001f * ln) / n;
        float sem = ce + dice;
        out[0] = sem + ins;
        out[1] = sem;
        out[2] = ce;
        out[3] = dice;
        out[4] = ins;
    }
}

extern "C" void kernel_launch(void* const* d_in, const int* in_sizes, int n_in,
                              void* d_out, int out_size, void* d_ws, size_t ws_size,
                              hipStream_t stream) {
    const float* sem = (const float*)d_in[0];
    const float* emb = (const float*)d_in[1];
    const int* cls = (const int*)d_in[2];
    const int* lab = (const int*)d_in[3];
    float* out = (float*)d_out;
    float* acc = (float*)d_ws;

    hipLaunchKernelGGL(zero_kernel, dim3(23), dim3(1024), 0, stream, acc);
    hipLaunchKernelGGL(phaseA_kernel, dim3(2816), dim3(256), 0, stream, sem, emb, cls, lab, acc);
    hipLaunchKernelGGL(centers_kernel, dim3(1), dim3(1024), 0, stream, acc);
    hipLaunchKernelGGL(phaseB_kernel, dim3(3328), dim3(256), 0, stream, sem, emb, cls, lab, acc);
    hipLaunchKernelGGL(finalize_kernel, dim3(1), dim3(256), 0, stream, acc, out);
}

// Round 7
// 306.255 us; speedup vs baseline: 1.7330x; 1.0012x over previous
//
#include <hip/hip_runtime.h>

#define DHW (64*128*128)
#define MIR 32

// accumulator layout in d_ws (floats)
#define OFF_CEM   0        // [MIR][49]: nll, cardp[2][8], inter[2][8], cardg[2][8]
#define OFF_SEGM  1568     // [MIR][2][306] (atomic-fallback path only)
#define OFF_PULLM 21152    // [MIR][2][17]
#define OFF_CTR   22240    // [2][17][16]
#define OFF_CNT   22784    // [2][17]
#define ACC_FLOATS 22818
#define OFF_EDGE_BYTES 92160   // byte offset: 2 * DHW/4 bytes = 512 KiB edge-bit cache (ends at float 154112)
#define OFF_SEGRAW 160000      // float offset: [2048][288] per-task raw seg stats (store path)

typedef __bf16 bf16x8 __attribute__((ext_vector_type(8)));
typedef float f32x4 __attribute__((ext_vector_type(4)));
union FragU { short s[8]; bf16x8 v; };

__device__ inline short f2bf(float f) {   // RTNE float->bf16
    union { float f; unsigned u; } v; v.f = f;
    unsigned r = v.u + 0x7FFF + ((v.u >> 16) & 1);
    return (short)(r >> 16);
}

__global__ void zero_kernel(float* acc) {
    int i = blockIdx.x * 1024 + threadIdx.x;
    if (i < ACC_FLOATS) acc[i] = 0.0f;
}

// ---------------- ce_dice role (1024-voxel tile) ----------------
__device__ void ce_role(const float* __restrict__ logits, const int* __restrict__ cls,
                        float* __restrict__ acc, int b, int blk, float* sh) {
    int tid = threadIdx.x;
    int mir = blk & (MIR - 1);
    int vb = (blk * 256 + tid) * 4;
    const float* lg = logits + (size_t)b * 8 * DHW;
    const int* cl = cls + (size_t)b * DHW;

    float4 xc[8];
#pragma unroll
    for (int c = 0; c < 8; ++c)
        xc[c] = *reinterpret_cast<const float4*>(&lg[(size_t)c * DHW + vb]);
    int4 t4 = *reinterpret_cast<const int4*>(&cl[vb]);
    int tt[4] = {t4.x, t4.y, t4.z, t4.w};

    float nll = 0.f, cardp[8], inter[8], cardg[8];
#pragma unroll
    for (int c = 0; c < 8; ++c) { cardp[c] = 0.f; inter[c] = 0.f; cardg[c] = 0.f; }

#pragma unroll
    for (int j = 0; j < 4; ++j) {
        float x[8];
#pragma unroll
        for (int c = 0; c < 8; ++c) x[c] = ((const float*)&xc[c])[j];
        int t = tt[j];
        bool valid = (t != -100);
        float mx = x[0];
#pragma unroll
        for (int c = 1; c < 8; ++c) mx = fmaxf(mx, x[c]);
        float e[8], s = 0.f;
#pragma unroll
        for (int c = 0; c < 8; ++c) { e[c] = __expf(x[c] - mx); s += e[c]; }
        float inv = 1.0f / s;
        float lse = __logf(s);
        if (valid) {
#pragma unroll
            for (int c = 0; c < 8; ++c) {
                float p = e[c] * inv;
                cardp[c] += p;
                if (t == c) { inter[c] += p; cardg[c] += 1.f; nll += mx + lse - x[c]; }
            }
        }
    }

    if (tid < 25) sh[tid] = 0.f;
    __syncthreads();
    int lane = tid & 63;
    float vals[25];
    vals[0] = nll;
#pragma unroll
    for (int c = 0; c < 8; ++c) { vals[1 + c] = cardp[c]; vals[9 + c] = inter[c]; vals[17 + c] = cardg[c]; }
#pragma unroll
    for (int i = 0; i < 25; ++i) {
        float r = vals[i];
#pragma unroll
        for (int off = 32; off > 0; off >>= 1) r += __shfl_down(r, off, 64);
        if (lane == 0) atomicAdd(&sh[i], r);
    }
    __syncthreads();
    if (tid < 25) {
        int dst;
        if (tid == 0) dst = 0;
        else if (tid < 9) dst = 1 + b * 8 + (tid - 1);
        else if (tid < 17) dst = 17 + b * 8 + (tid - 9);
        else dst = 33 + b * 8 + (tid - 17);
        atomicAdd(&acc[OFF_CEM + mir * 49 + dst], sh[tid]);
    }
}

// ---------------- phase A: seg (LDS-staged labels) + ce ----------------
// STORE=1: per-task unique plain stores (no global atomics on the seg path)
// STORE=0: round-4 mirrored atomic writeback (fallback if ws too small)
template<int STORE>
__global__ __launch_bounds__(256) void phaseA_kernel(const float* __restrict__ logits,
                                                     const float* __restrict__ embed,
                                                     const int* __restrict__ cls,
                                                     const int* __restrict__ labels,
                                                     float* __restrict__ acc) {
    __shared__ int s_tile[3840];            // 3 z * 10 y-rows * 128 x labels
    __shared__ unsigned char s_eb[256];     // edge bits, 1 byte per 4 voxels
    __shared__ float s_cacc[288];
    int x = blockIdx.x;
    int g = x / 11, r3 = x % 11;
    int tid = threadIdx.x;

    if (r3 >= 8) {              // ce role: 3 per group of 11 -> 768 tiles
        int ce_idx = g * 3 + (r3 - 8);       // [0,768)
        int b = (ce_idx >= 384) ? 1 : 0;
        int blk = ce_idx - b * 384;          // [0,384)
        ce_role(logits, cls, acc, b, blk, s_cacc);
        return;
    }
    // seg role
    int seg_idx = g * 8 + r3;   // [0,2048)
    int b = seg_idx & 1;
    int blk = seg_idx >> 1;     // [0,1024)
    int mir = blk & (MIR - 1);
    int lane = tid & 63;
    int wv = tid >> 6;
    int m = lane & 15;          // A-row (label m+1) / B-col (channel m)
    int quad = lane >> 4;

    const int* L = labels + (size_t)b * DHW;
    const float* E = embed + (size_t)b * 16 * DHW + (size_t)m * DHW;

    int vb0 = blk * 1024;
    int z0 = vb0 >> 14;
    int y0 = (vb0 >> 7) & 127;

    // stage 30 label rows (z0-1..z0+1 x y0-1..y0+8, edge-clamped) into LDS
    for (int idx = tid; idx < 960; idx += 256) {
        int row = idx >> 5, col = idx & 31;       // col in int4 units
        int zi = row / 10, ri = row - zi * 10;
        int zz = min(max(z0 + zi - 1, 0), 63);
        int yy = min(max(y0 + ri - 1, 0), 127);
        reinterpret_cast<int4*>(s_tile)[row * 32 + col] =
            *reinterpret_cast<const int4*>(&L[(zz << 14) + (yy << 7) + col * 4]);
    }
    __syncthreads();

    // edge bits for own 4 voxels (voxel base tid*4 within the 1024) from LDS
    {
        int p = tid * 4;
        int xx = p & 127, lr = p >> 7;            // local row 0..7 -> tile ri = lr+1
        int xm = max(xx - 1, 0), xp = min(xx + 4, 127);
        const int* crow = &s_tile[(10 + lr + 1) * 128];
        int4 c; c.x = crow[xx]; c.y = crow[xx + 1]; c.z = crow[xx + 2]; c.w = crow[xx + 3];
        unsigned b0 = 0, b1 = 0, b2 = 0, b3 = 0;
#pragma unroll
        for (int zi = 0; zi < 3; ++zi) {
#pragma unroll
            for (int dy = 0; dy < 3; ++dy) {
                const int* row = &s_tile[(zi * 10 + lr + dy) * 128];
                int rx = row[xx], ry = row[xx + 1], rz = row[xx + 2], rw = row[xx + 3];
                int rm = row[xm], rp = row[xp];
                b0 |= (rm != c.x) | (rx != c.x) | (ry != c.x);
                b1 |= (rx != c.y) | (ry != c.y) | (rz != c.y);
                b2 |= (ry != c.z) | (rz != c.z) | (rw != c.z);
                b3 |= (rz != c.w) | (rw != c.w) | (rp != c.w);
            }
        }
        unsigned eb_own = b0 | (b1 << 1) | (b2 << 2) | (b3 << 3);
        s_eb[tid] = (unsigned char)eb_own;
        unsigned char* EB = (unsigned char*)acc + OFF_EDGE_BYTES + ((size_t)b << 18);
        EB[blk * 256 + tid] = (unsigned char)eb_own;
    }
    __syncthreads();

    int lo0 = wv * 256 + quad * 8;   // local offset of this lane's first 8-voxel chunk

    f32x4 acc_c = {0.f, 0.f, 0.f, 0.f};
    f32x4 acc_w = {0.f, 0.f, 0.f, 0.f};
    f32x4 acc_n = {0.f, 0.f, 0.f, 0.f};

    FragU ones_col;
#pragma unroll
    for (int j = 0; j < 8; ++j) ones_col.s[j] = (m == 0) ? (short)0x3F80 : (short)0;

    // depth-2 prefetch on the embed stream only (labels come from LDS)
    int goff = vb0 + lo0;
    float4 Fa0 = *reinterpret_cast<const float4*>(&E[goff]);
    float4 Fa1 = *reinterpret_cast<const float4*>(&E[goff + 4]);
    float4 Fb0 = *reinterpret_cast<const float4*>(&E[goff + 32]);
    float4 Fb1 = *reinterpret_cast<const float4*>(&E[goff + 36]);

#pragma unroll
    for (int i = 0; i < 8; ++i) {
        float4 cf0, cf1;
        if (i & 1) { cf0 = Fb0; cf1 = Fb1; }
        else       { cf0 = Fa0; cf1 = Fa1; }
        if (i < 6) {
            int noff = goff + (i + 2) * 32;
            if (i & 1) {
                Fb0 = *reinterpret_cast<const float4*>(&E[noff]);
                Fb1 = *reinterpret_cast<const float4*>(&E[noff + 4]);
            } else {
                Fa0 = *reinterpret_cast<const float4*>(&E[noff]);
                Fa1 = *reinterpret_cast<const float4*>(&E[noff + 4]);
            }
        }
        // labels for this chunk from the LDS tile (central z, rows 1..8)
        int lo = lo0 + i * 32;
        const int* rowp = &s_tile[(10 + (lo >> 7) + 1) * 128 + (lo & 127)];
        // edge bits for the 8 voxels of this K-slice
        int s0 = i * 8 + quad * 2;
        unsigned short u = *reinterpret_cast<const unsigned short*>(&s_eb[wv * 64 + s0]);
        unsigned eb = (u & 0xF) | ((u >> 4) & 0xF0);

        FragU a, a2, bf;
#pragma unroll
        for (int j = 0; j < 8; ++j) {
            short w = ((eb >> j) & 1) ? (short)0x4120 : (short)0x3F80;   // 10.0 : 1.0
            bool hit = (rowp[j] == m + 1);
            a.s[j]  = hit ? w : (short)0;
            a2.s[j] = hit ? (short)0x3F80 : (short)0;
            float fv = (j < 4) ? ((const float*)&cf0)[j] : ((const float*)&cf1)[j - 4];
            bf.s[j] = f2bf(fv);
        }
        acc_c = __builtin_amdgcn_mfma_f32_16x16x32_bf16(a.v, bf.v, acc_c, 0, 0, 0);
        acc_w = __builtin_amdgcn_mfma_f32_16x16x32_bf16(a.v, ones_col.v, acc_w, 0, 0, 0);
        acc_n = __builtin_amdgcn_mfma_f32_16x16x32_bf16(a2.v, ones_col.v, acc_n, 0, 0, 0);
    }

    for (int i = tid; i < 288; i += 256) s_cacc[i] = 0.f;
    __syncthreads();
#pragma unroll
    for (int rr = 0; rr < 4; ++rr)
        atomicAdd(&s_cacc[(quad * 4 + rr) * 16 + m], acc_c[rr]);
    if (m == 0) {
#pragma unroll
        for (int rr = 0; rr < 4; ++rr) {
            atomicAdd(&s_cacc[256 + quad * 4 + rr], acc_w[rr]);
            atomicAdd(&s_cacc[272 + quad * 4 + rr], acc_n[rr]);
        }
    }
    __syncthreads();
    if (STORE) {
        // plain stores to a per-task-unique 288-float slot (no global atomics)
        float* segp = acc + OFF_SEGRAW + (size_t)seg_idx * 288;
        segp[tid] = s_cacc[tid];
        if (tid < 32) segp[256 + tid] = s_cacc[256 + tid];
    } else {
        float* segbase = acc + OFF_SEGM + mir * 612 + b * 306;
        atomicAdd(&segbase[16 + tid], s_cacc[tid]);
        if (tid < 16) atomicAdd(&segbase[272 + 1 + tid], s_cacc[256 + tid]);
        else if (tid < 32) atomicAdd(&segbase[289 + 1 + (tid - 16)], s_cacc[256 + tid]);
    }
}

// ---------------- centers from raw per-task slots (store path) ----------------
__global__ __launch_bounds__(256) void centers_raw_kernel(float* acc) {
    int j = blockIdx.x;            // 0..33: b = j/17, k = j%17
    int b = j / 17, k = j % 17;
    int tid = threadIdx.x;
    if (k == 0) {                   // label-0 slots: centers row = 0, cnt = 0
        if (tid < 16) acc[OFF_CTR + b * 272 + tid] = 0.f;
        if (tid == 16) acc[OFF_CNT + b * 17] = 0.f;
        return;
    }
    float vals[18];
#pragma unroll
    for (int i = 0; i < 18; ++i) vals[i] = 0.f;
    for (int t = tid; t < 1024; t += 256) {
        const float* sp = acc + OFF_SEGRAW + (size_t)(2 * t + b) * 288;
        const float* row = sp + (k - 1) * 16;
#pragma unroll
        for (int c = 0; c < 16; ++c) vals[c] += row[c];
        vals[16] += sp[256 + (k - 1)];
        vals[17] += sp[272 + (k - 1)];
    }
    __shared__ float sh[18];
    if (tid < 18) sh[tid] = 0.f;
    __syncthreads();
    int lane = tid & 63;
#pragma unroll
    for (int i = 0; i < 18; ++i) {
        float r = vals[i];
#pragma unroll
        for (int off = 32; off > 0; off >>= 1) r += __shfl_down(r, off, 64);
        if (lane == 0) atomicAdd(&sh[i], r);
    }
    __syncthreads();
    if (tid < 16) acc[OFF_CTR + b * 272 + k * 16 + tid] = sh[tid] / (sh[16] + 1e-8f);
    if (tid == 16) acc[OFF_CNT + b * 17 + k] = sh[17];
}

// ---------------- centers from mirrors (atomic-fallback path) ----------------
__global__ __launch_bounds__(1024) void centers_kernel(float* acc) {
    int tid = threadIdx.x;
    if (tid < 544) {
        int b = tid / 272, r = tid % 272;       // r = k*16+c
        int k = r >> 4;
        float cn = 0.f, ws = 0.f;
        for (int mv = 0; mv < MIR; ++mv) {
            const float* segbase = acc + OFF_SEGM + mv * 612 + b * 306;
            if (r >= 16) cn += segbase[r];
            ws += segbase[272 + k];
        }
        acc[OFF_CTR + tid] = (r >= 16) ? cn / (ws + 1e-8f) : 0.f;
    } else if (tid < 578) {
        int j = tid - 544;                       // b*17+k
        int b = j / 17, k = j % 17;
        float s = 0.f;
        for (int mv = 0; mv < MIR; ++mv)
            s += acc[OFF_SEGM + mv * 612 + b * 306 + 289 + k];
        acc[OFF_CNT + j] = s;
    }
}

// ---------------- phase B: pull + ce ----------------
__global__ __launch_bounds__(256) void phaseB_kernel(const float* __restrict__ logits,
                                                     const float* __restrict__ embed,
                                                     const int* __restrict__ cls,
                                                     const int* __restrict__ labels,
                                                     float* __restrict__ acc) {
    __shared__ float smem[352];
    int x = blockIdx.x;
    int g = x / 13, r3 = x % 13;
    int tid = threadIdx.x;

    if (r3 >= 8) {              // ce role: 5 per group of 13 -> 1280 tiles
        int ce_idx = g * 5 + (r3 - 8);       // [0,1280)
        int b = (ce_idx >= 640) ? 1 : 0;
        int blk = 384 + (ce_idx - b * 640);  // [384,1024)
        ce_role(logits, cls, acc, b, blk, smem);
        return;
    }
    // pull role
    int pull_idx = g * 8 + r3;  // [0,2048)
    int b = pull_idx & 1;
    int blk = pull_idx >> 1;    // [0,1024)
    int wv = tid >> 6;
    float* ctr = smem;          // 272
    float* ps = smem + 272;     // 80
    for (int i = tid; i < 272; i += 256) ctr[i] = acc[OFF_CTR + b * 272 + i];
    for (int i = tid; i < 80; i += 256) ps[i] = 0.f;
    __syncthreads();

    const int* L = labels + (size_t)b * DHW;
    const float* E = embed + (size_t)b * 16 * DHW;
    int vb = (blk * 256 + tid) * 4;

    int4 l4 = *reinterpret_cast<const int4*>(&L[vb]);
    int l[4] = {l4.x, l4.y, l4.z, l4.w};
    unsigned eb;
    {
        const unsigned char* EB = (const unsigned char*)acc + OFF_EDGE_BYTES + ((size_t)b << 18);
        eb = EB[blk * 256 + tid];
    }

    // hoist all 16 embed loads (independent, max MLP)
    float4 ev[16];
#pragma unroll
    for (int c = 0; c < 16; ++c)
        ev[c] = *reinterpret_cast<const float4*>(&E[(size_t)c * DHW + vb]);

    float d2a[4] = {0.f, 0.f, 0.f, 0.f};
#pragma unroll
    for (int q = 0; q < 4; ++q) {
#pragma unroll
        for (int j = 0; j < 4; ++j) {
            if (l[j] != 0) {
                float4 cv = *reinterpret_cast<const float4*>(&ctr[l[j] * 16 + q * 4]);
                float d0 = ((const float*)&ev[4 * q + 0])[j] - cv.x;
                float d1 = ((const float*)&ev[4 * q + 1])[j] - cv.y;
                float d2 = ((const float*)&ev[4 * q + 2])[j] - cv.z;
                float d3 = ((const float*)&ev[4 * q + 3])[j] - cv.w;
                d2a[j] += d0 * d0 + d1 * d1 + d2 * d2 + d3 * d3;
            }
        }
    }

#pragma unroll
    for (int j = 0; j < 4; ++j) {
        if (l[j] != 0) {
            float w = ((eb >> j) & 1) ? 10.f : 1.f;
            float d = fmaxf(sqrtf(d2a[j]) - 0.5f, 0.f);
            atomicAdd(&ps[wv * 20 + l[j]], d * d * w);
        }
    }
    __syncthreads();
    if (tid >= 1 && tid < 17) {
        float v = ps[tid] + ps[20 + tid] + ps[40 + tid] + ps[60 + tid];
        int mir = blk & (MIR - 1);
        if (v != 0.f) atomicAdd(&acc[OFF_PULLM + mir * 34 + b * 17 + tid], v);
    }
}

// ---------------- finalize ----------------
__global__ __launch_bounds__(256) void finalize_kernel(const float* __restrict__ acc, float* __restrict__ out) {
    __shared__ float s_ce[49], s_pl[34];
    __shared__ float sh_push[2], sh_norm[2], sh_pull[2], sh_npres[2];
    int tid = threadIdx.x;
    if (tid < 49) {
        float s = 0.f;
        for (int mv = 0; mv < MIR; ++mv) s += acc[OFF_CEM + mv * 49 + tid];
        s_ce[tid] = s;
    }
    if (tid >= 64 && tid < 98) {
        int j = tid - 64;
        float s = 0.f;
        for (int mv = 0; mv < MIR; ++mv) s += acc[OFF_PULLM + mv * 34 + j];
        s_pl[j] = s;
    }
    if (tid < 2) { sh_push[tid] = 0.f; sh_norm[tid] = 0.f; sh_pull[tid] = 0.f; sh_npres[tid] = 0.f; }
    __syncthreads();

    if (tid < 32) {
        int b = tid >> 4, k = (tid & 15) + 1;
        float cnt = acc[OFF_CNT + b * 17 + k];
        if (cnt > 0.f) {
            atomicAdd(&sh_npres[b], 1.f);
            atomicAdd(&sh_pull[b], s_pl[b * 17 + k] / fmaxf(cnt, 1.f));
            const float* c = &acc[OFF_CTR + (b * 17 + k) * 16];
            float n2 = 0.f;
            for (int i = 0; i < 16; ++i) n2 += c[i] * c[i];
            atomicAdd(&sh_norm[b], sqrtf(n2));
        }
    }
    for (int t = tid; t < 240; t += blockDim.x) {
        int b = t / 120, p = t % 120;
        int i = 1, rem = p;
        while (rem >= (16 - i)) { rem -= (16 - i); ++i; }
        int j = i + 1 + rem;
        bool pi = acc[OFF_CNT + b * 17 + i] > 0.f;
        bool pj = acc[OFF_CNT + b * 17 + j] > 0.f;
        if (pi && pj) {
            const float* ci = &acc[OFF_CTR + (b * 17 + i) * 16];
            const float* cj = &acc[OFF_CTR + (b * 17 + j) * 16];
            float d2 = 0.f;
            for (int c = 0; c < 16; ++c) { float dd = ci[c] - cj[c]; d2 += dd * dd; }
            float r = fmaxf(3.0f - sqrtf(d2), 0.f);
            atomicAdd(&sh_push[b], r * r);
        }
    }
    __syncthreads();
    if (tid == 0) {
        float nll = s_ce[0];
        float vcnt = 0.f;
        for (int i = 0; i < 16; ++i) vcnt += s_ce[33 + i];
        float ce = nll / fmaxf(vcnt, 1.f);
        float dsum = 0.f;
        for (int i = 0; i < 16; ++i) {
            float it = s_ce[17 + i], cp = s_ce[1 + i], cg = s_ce[33 + i];
            dsum += (2.f * it + 1e-5f) / (cp + cg + 1e-5f);
        }
        float dice = 1.f - dsum / 16.f;
        float lp = 0.f, lpu = 0.f, ln = 0.f, val = 0.f;
        for (int b = 0; b < 2; ++b) {
            float npres = sh_npres[b];
            lp += sh_pull[b];
            float npairs = npres * (npres - 1.f) * 0.5f;
            lpu += (npairs > 0.f) ? sh_push[b] / fmaxf(npairs, 1.f) : 0.f;
            ln += (npres > 0.f) ? sh_norm[b] / fmaxf(npres, 1.f) : 0.f;
            val += (npres > 0.f) ? 1.f : 0.f;
        }
        float n = fmaxf(val, 1.f);
        float ins = (1.0f * lp + 1.0f * lpu + 0.001f * ln) / n;
        float sem = ce + dice;
        out[0] = sem + ins;
        out[1] = sem;
        out[2] = ce;
        out[3] = dice;
        out[4] = ins;
    }
}

extern "C" void kernel_launch(void* const* d_in, const int* in_sizes, int n_in,
                              void* d_out, int out_size, void* d_ws, size_t ws_size,
                              hipStream_t stream) {
    const float* sem = (const float*)d_in[0];
    const float* emb = (const float*)d_in[1];
    const int* cls = (const int*)d_in[2];
    const int* lab = (const int*)d_in[3];
    float* out = (float*)d_out;
    float* acc = (float*)d_ws;

    size_t need = ((size_t)OFF_SEGRAW + 2048ull * 288ull) * 4ull;   // ~3.0 MB
    bool store_path = (ws_size >= need);

    hipLaunchKernelGGL(zero_kernel, dim3(23), dim3(1024), 0, stream, acc);
    if (store_path) {
        hipLaunchKernelGGL((phaseA_kernel<1>), dim3(2816), dim3(256), 0, stream, sem, emb, cls, lab, acc);
        hipLaunchKernelGGL(centers_raw_kernel, dim3(34), dim3(256), 0, stream, acc);
    } else {
        hipLaunchKernelGGL((phaseA_kernel<0>), dim3(2816), dim3(256), 0, stream, sem, emb, cls, lab, acc);
        hipLaunchKernelGGL(centers_kernel, dim3(1), dim3(1024), 0, stream, acc);
    }
    hipLaunchKernelGGL(phaseB_kernel, dim3(3328), dim3(256), 0, stream, sem, emb, cls, lab, acc);
    hipLaunchKernelGGL(finalize_kernel, dim3(1), dim3(256), 0, stream, acc, out);
}